// Round 8
// baseline (146.482 us; speedup 1.0000x reference)
//
#include <hip/hip_runtime.h>
#include <math.h>

#define Bn 32
#define Rn 512
#define Dn 256
#define Pn 5532
#define MAXU 512
#define NEGBIG -3.0e38f

typedef short short8 __attribute__((ext_vector_type(8)));
typedef short short4v __attribute__((ext_vector_type(4)));
typedef float floatx4 __attribute__((ext_vector_type(4)));

// ---- workspace layout (4-byte words). NOTHING is pre-zeroed; every word read
// is written earlier in the same call (poison-safe).
#define XBF_OFF    0
#define XBF_WORDS  (Bn*Rn*Dn/2)
#define PBF_OFF    (XBF_OFF + XBF_WORDS)
#define PBF_WORDS  (Bn*MAXU*Dn/2)
#define CMAP_OFF   (PBF_OFF + PBF_WORDS)
#define CCNT_OFF   (CMAP_OFF + Bn*Pn)
#define CURS_OFF   (CCNT_OFF + Bn*MAXU)
#define RLIST_OFF  (CURS_OFF + Bn*MAXU)
#define NUNIQ_OFF  (RLIST_OFF + Bn*Rn)
#define NVALID_OFF (NUNIQ_OFF + 32)
#define MPART_OFF  (NVALID_OFF + 32)
#define SPART_OFF  (MPART_OFF + Bn*Rn*4)
#define DLBL_OFF   (SPART_OFF + Bn*Rn*4)
// end ~= 4.57M words ~= 18.3 MB

__device__ __forceinline__ unsigned short bf16r(float f) {   // fp32 -> bf16 RNE
    union { float f; unsigned int u; } c; c.f = f;
    return (unsigned short)((c.u + 0x7FFFu + ((c.u >> 16) & 1u)) >> 16);
}

// async global->LDS, 16B per lane. LDS dest = wave-uniform base + lane*16.
__device__ __forceinline__ void async16(void* lds, const void* g) {
    auto* l3 = reinterpret_cast<__attribute__((address_space(3))) unsigned int*>(
                   reinterpret_cast<size_t>(lds));
    auto* g1 = reinterpret_cast<const __attribute__((address_space(1))) unsigned int*>(
                   reinterpret_cast<size_t>(g));
    __builtin_amdgcn_global_load_lds(g1, l3, 16, 0, 0);
}

// ======== k1: blocks 0..31 = in-LDS per-image compact; blocks 32..543 = convert ======
__global__ __launch_bounds__(1024) void k1_prep_compact(
    const float* __restrict__ inputs, const float* __restrict__ cls,
    const int* __restrict__ roi_label,
    unsigned short* __restrict__ xbf,
    int* __restrict__ cmap, int* __restrict__ ccnt, int* __restrict__ cursor,
    int* __restrict__ rlist, int* __restrict__ nuniq, int* __restrict__ nvalid_arr)
{
    const int flat = blockIdx.x;
    const int t = threadIdx.x;

    __shared__ int cnt_lds[Pn];                       // 22.1 KB
    __shared__ int cmap_lds[Pn];                      // 22.1 KB
    __shared__ int curs_lds[MAXU];
    __shared__ int wpres[16], wcnt[16];

    if (flat >= 32) {
        // ---- convert inputs*cls -> bf16: 512 blocks x 1024 thr x 8 elems ----
        int g = (flat - 32) * 1024 + t;               // 0..524287
        int e = g * 8;
        int row = e >> 8;                             // /Dn
        float cw = cls[row];
        float4 v0 = *(const float4*)&inputs[e];
        float4 v1 = *(const float4*)&inputs[e + 4];
        short8 o;
        o[0] = (short)bf16r(v0.x * cw); o[1] = (short)bf16r(v0.y * cw);
        o[2] = (short)bf16r(v0.z * cw); o[3] = (short)bf16r(v0.w * cw);
        o[4] = (short)bf16r(v1.x * cw); o[5] = (short)bf16r(v1.y * cw);
        o[6] = (short)bf16r(v1.z * cw); o[7] = (short)bf16r(v1.w * cw);
        *(short8*)&xbf[e] = o;
        return;
    }

    // ---- per-image compact (R6 k_compact body; counts from LDS, not global) ----
    const int b = flat;
    const int lane = t & 63, wid = t >> 6;            // 16 waves
    for (int i = t; i < Pn; i += 1024) cnt_lds[i] = 0;
    __syncthreads();
    if (t < Rn) {
        int lbl = roi_label[b * Rn + t] - 1;
        if (lbl >= 0) atomicAdd(&cnt_lds[lbl], 1);
    }
    __syncthreads();

    int basePres = 0, baseCnt = 0;                    // replicated in all threads
    for (int i0 = 0; i0 < Pn; i0 += 1024) {
        int i = i0 + t;
        int cnt = (i < Pn) ? cnt_lds[i] : 0;
        bool pres = cnt > 0;
        unsigned long long mask = __ballot(pres);
        int pfx_pres = __popcll(mask & ((1ULL << lane) - 1ULL));
        int v = cnt;
        #pragma unroll
        for (int off = 1; off < 64; off <<= 1) {
            int u = __shfl_up(v, off);
            if (lane >= off) v += u;
        }
        int pfx_cnt = v - cnt;                        // exclusive
        if (lane == 63) { wpres[wid] = __popcll(mask); wcnt[wid] = v; }
        __syncthreads();
        int woffP = 0, totP = 0, woffC = 0, totC = 0;
        #pragma unroll
        for (int w = 0; w < 16; ++w) {
            int p = wpres[w], c = wcnt[w];
            if (w < wid) { woffP += p; woffC += c; }
            totP += p; totC += c;
        }
        if (pres) {
            int c = basePres + woffP + pfx_pres;      // compact slot < MAXU
            cmap_lds[i] = c;
            cmap[b * Pn + i] = c;                     // k3 lookup
            ccnt[b * MAXU + c] = cnt;
            curs_lds[c] = baseCnt + woffC + pfx_cnt;  // start offset
        }
        basePres += totP; baseCnt += totC;
        __syncthreads();
    }
    // scatter this image's 512 ROIs via LDS atomics
    if (t < Rn) {
        int lbl = roi_label[b * Rn + t] - 1;
        if (lbl >= 0) {
            int c = cmap_lds[lbl];
            int pos = atomicAdd(&curs_lds[c], 1);
            rlist[b * Rn + pos] = t;
        }
    }
    __syncthreads();
    if (t < MAXU && t < basePres)
        cursor[b * MAXU + t] = curs_lds[t];           // end offset (= start + cnt)
    if (t == 0) { nuniq[b] = basePres; nvalid_arr[b] = baseCnt; }
}

// ======== k2: gather -> mean -> L2 normalize -> bf16 proto (one wave, 8 slots) ======
__global__ __launch_bounds__(64) void k2_proto(
    const float* __restrict__ inputs, const float* __restrict__ cls,
    const int* __restrict__ nuniq, const int* __restrict__ ccnt,
    const int* __restrict__ cursor, const int* __restrict__ rlist,
    unsigned short* __restrict__ pbf)
{
    int t = threadIdx.x;
    int s0 = blockIdx.x * 8;
    for (int s = s0; s < s0 + 8; ++s) {
        int b = s >> 9;
        int c = s & (MAXU - 1);
        if (c >= nuniq[b]) continue;
        int cnt = ccnt[s];
        int start = cursor[s] - cnt;
        float4 acc = make_float4(0.f, 0.f, 0.f, 0.f);
        for (int k = 0; k < cnt; ++k) {
            int r = rlist[b * Rn + start + k];
            float cw = cls[b * Rn + r];
            float4 v = *(const float4*)&inputs[(size_t)(b * Rn + r) * Dn + t * 4];
            acc.x += v.x * cw; acc.y += v.y * cw; acc.z += v.z * cw; acc.w += v.w * cw;
        }
        float inv = 1.0f / (float)cnt;
        acc.x *= inv; acc.y *= inv; acc.z *= inv; acc.w *= inv;
        float ss = acc.x*acc.x + acc.y*acc.y + acc.z*acc.z + acc.w*acc.w;
        #pragma unroll
        for (int off = 32; off > 0; off >>= 1) ss += __shfl_xor(ss, off);
        float scale = 1.0f / fmaxf(sqrtf(ss), 1e-12f);
        short4v o;
        o[0] = (short)bf16r(acc.x * scale); o[1] = (short)bf16r(acc.y * scale);
        o[2] = (short)bf16r(acc.z * scale); o[3] = (short)bf16r(acc.w * scale);
        *(short4v*)&pbf[(size_t)s * Dn + t * 4] = o;
    }
}

// ======== k3: bf16 MFMA GEMM, 128x128 tiles, async dbuf LDS + logsumexp (R6) ========
#define TRr 128
#define TCc 128
#define KCk 32

__global__ __launch_bounds__(256, 3) void k3_loss(
    const unsigned short* __restrict__ xbf, const unsigned short* __restrict__ pbf,
    const int* __restrict__ roi_label, const int* __restrict__ cmap,
    const int* __restrict__ nuniq,
    float* __restrict__ mpart, float* __restrict__ spart,
    float* __restrict__ dlbl_arr)
{
    // XOR-swizzled bf16 tiles (content group g at gpos = g ^ ((row>>1)&3)),
    // realized via per-lane GLOBAL address; LDS side stays lane*16-linear.
    __shared__ __align__(16) unsigned short xs[2][TRr * KCk];   // 2 x 8 KB
    __shared__ __align__(16) unsigned short ps[2][TCc * KCk];   // 2 x 8 KB
    __shared__ int lblc[TRr];
    __shared__ float mw[4][TRr], sw[4][TRr];

    const int t = threadIdx.x;
    const int lane = t & 63, w = t >> 6;
    const int q = lane >> 4, r15 = lane & 15;
    const int b = blockIdx.z;
    const int pc = blockIdx.y;
    const int roiBase = blockIdx.x * TRr;
    const int U = nuniq[b];
    if (pc * TCc >= U) return;                        // uniform block exit

    if (t < TRr) {
        int lbl = roi_label[b * Rn + roiBase + t] - 1;
        lblc[t] = (lbl >= 0) ? cmap[b * Pn + lbl] : -1;
    }

    // 16 chunks/stage (8 xs + 8 ps); wave w stages xs {w, w+4}, ps {w, w+4}.
    int xrow[2], xg[2];
    #pragma unroll
    for (int cc = 0; cc < 2; ++cc) {
        int s = (w + cc * 4) * 64 + lane;
        xrow[cc] = s >> 2; xg[cc] = (s & 3) ^ ((xrow[cc] >> 1) & 3);
    }

    #define ISSUE(kc, buf)                                                         \
        do {                                                                       \
            async16(&xs[buf][w * 512],                                             \
                    xbf + (size_t)(b * Rn + roiBase + xrow[0]) * Dn                \
                        + (kc) * KCk + xg[0] * 8);                                 \
            async16(&xs[buf][(w + 4) * 512],                                       \
                    xbf + (size_t)(b * Rn + roiBase + xrow[1]) * Dn                \
                        + (kc) * KCk + xg[1] * 8);                                 \
            async16(&ps[buf][w * 512],                                             \
                    pbf + (size_t)(b * MAXU + pc * TCc + xrow[0]) * Dn             \
                        + (kc) * KCk + xg[0] * 8);                                 \
            async16(&ps[buf][(w + 4) * 512],                                       \
                    pbf + (size_t)(b * MAXU + pc * TCc + xrow[1]) * Dn             \
                        + (kc) * KCk + xg[1] * 8);                                 \
        } while (0)

    ISSUE(0, 0);

    floatx4 acc[8][2];
    #pragma unroll
    for (int mt = 0; mt < 8; ++mt)
        #pragma unroll
        for (int nt = 0; nt < 2; ++nt) acc[mt][nt] = (floatx4)0.f;

    for (int kc = 0; kc < Dn / KCk; ++kc) {           // 8 stages
        const int cur = kc & 1;
        __syncthreads();                              // buf[cur] resident
        if (kc < Dn / KCk - 1) ISSUE(kc + 1, cur ^ 1);

        short8 bb[2];
        #pragma unroll
        for (int nt = 0; nt < 2; ++nt) {
            int row = w * 32 + nt * 16 + r15;
            int off = row * KCk + ((q ^ ((row >> 1) & 3)) * 8);
            bb[nt] = *(const short8*)&ps[cur][off];
        }
        #pragma unroll
        for (int mt = 0; mt < 8; ++mt) {
            int row = mt * 16 + r15;
            int off = row * KCk + ((q ^ ((row >> 1) & 3)) * 8);
            short8 a = *(const short8*)&xs[cur][off];
            acc[mt][0] = __builtin_amdgcn_mfma_f32_16x16x32_bf16(a, bb[0], acc[mt][0], 0, 0, 0);
            acc[mt][1] = __builtin_amdgcn_mfma_f32_16x16x32_bf16(a, bb[1], acc[mt][1], 0, 0, 0);
        }
    }
    #undef ISSUE

    // ---- epilogue: masked logsumexp; C/D layout n = r15, m = q*4 + reg (tile mt) ----
    const int c0 = pc * TCc + w * 32 + r15;
    const int c1 = c0 + 16;
    const bool v0 = c0 < U, v1 = c1 < U;
    #pragma unroll
    for (int mt = 0; mt < 8; ++mt)
        #pragma unroll
        for (int reg = 0; reg < 4; ++reg) {
            int mloc = mt * 16 + q * 4 + reg;
            float d0 = acc[mt][0][reg], d1 = acc[mt][1][reg];
            int lc = lblc[mloc];
            if (v0 && c0 == lc) dlbl_arr[b * Rn + roiBase + mloc] = d0;  // unique writer
            if (v1 && c1 == lc) dlbl_arr[b * Rn + roiBase + mloc] = d1;
            float M = fmaxf(v0 ? d0 : NEGBIG, v1 ? d1 : NEGBIG);
            #pragma unroll
            for (int off = 1; off < 16; off <<= 1) M = fmaxf(M, __shfl_xor(M, off));
            float s = (v0 ? __expf(d0 - M) : 0.f) + (v1 ? __expf(d1 - M) : 0.f);
            #pragma unroll
            for (int off = 1; off < 16; off <<= 1) s += __shfl_xor(s, off);
            if (r15 == 0) { mw[w][mloc] = M; sw[w][mloc] = s; }
        }
    __syncthreads();

    if (t < TRr) {
        float M = fmaxf(fmaxf(mw[0][t], mw[1][t]), fmaxf(mw[2][t], mw[3][t]));
        float s = 0.f;
        #pragma unroll
        for (int wv = 0; wv < 4; ++wv) s += sw[wv][t] * __expf(mw[wv][t] - M);
        int roi = b * Rn + roiBase + t;
        mpart[roi * 4 + pc] = M;
        spart[roi * 4 + pc] = s;
    }
}

// ======== k4: single-block merge + finalize (no atomics, no zero-init) ========
__global__ __launch_bounds__(1024) void k4_merge(
    const int* __restrict__ roi_label, const int* __restrict__ nuniq,
    const float* __restrict__ mpart, const float* __restrict__ spart,
    const float* __restrict__ dlbl_arr, const int* __restrict__ nvalid_arr,
    float* __restrict__ out)
{
    __shared__ float wsum[16];
    const int t = threadIdx.x;
    const int lane = t & 63, wid = t >> 6;
    float v = 0.f;
    for (int roi = t; roi < Bn * Rn; roi += 1024) {
        int b = roi >> 9;
        int lbl = roi_label[roi] - 1;
        if (lbl >= 0) {
            int U = nuniq[b];
            int nch = (U + TCc - 1) / TCc;
            float m = NEGBIG, s = 0.f;
            for (int pc = 0; pc < nch; ++pc) {
                float om = mpart[roi * 4 + pc], os = spart[roi * 4 + pc];
                float M = fmaxf(m, om);
                s = s * __expf(m - M) + os * __expf(om - M);
                m = M;
            }
            v += m + __logf(s) - dlbl_arr[roi];
        }
    }
    #pragma unroll
    for (int off = 1; off < 64; off <<= 1) v += __shfl_xor(v, off);
    if (lane == 0) wsum[wid] = v;
    __syncthreads();
    if (t < 64) {                                     // wave 0 finishes
        float x = (t < 16) ? wsum[t] : 0.f;
        #pragma unroll
        for (int off = 1; off < 64; off <<= 1) x += __shfl_xor(x, off);
        int nv = (t < Bn) ? nvalid_arr[t] : 0;
        #pragma unroll
        for (int off = 1; off < 64; off <<= 1) nv += __shfl_xor(nv, off);
        if (t == 0) out[0] = x / fmaxf((float)nv, 1.0f);
    }
}

extern "C" void kernel_launch(void* const* d_in, const int* in_sizes, int n_in,
                              void* d_out, int out_size, void* d_ws, size_t ws_size,
                              hipStream_t stream) {
    const float* inputs = (const float*)d_in[0];
    const float* cls    = (const float*)d_in[1];
    const int*   roi    = (const int*)d_in[2];
    float* out = (float*)d_out;

    float* wsf = (float*)d_ws;
    int*   wsi = (int*)d_ws;
    unsigned short* xbf = (unsigned short*)(wsi + XBF_OFF);
    unsigned short* pbf = (unsigned short*)(wsi + PBF_OFF);
    int*   cmap   = wsi + CMAP_OFF;
    int*   ccnt   = wsi + CCNT_OFF;
    int*   cursor = wsi + CURS_OFF;
    int*   rlist  = wsi + RLIST_OFF;
    int*   nuniq  = wsi + NUNIQ_OFF;
    int*   nvalid = wsi + NVALID_OFF;
    float* mpart  = wsf + MPART_OFF;
    float* spart  = wsf + SPART_OFF;
    float* dlbl   = wsf + DLBL_OFF;

    k1_prep_compact<<<32 + 512, 1024, 0, stream>>>(inputs, cls, roi, xbf, cmap, ccnt,
                                                   cursor, rlist, nuniq, nvalid);
    k2_proto<<<(Bn * MAXU) / 8, 64, 0, stream>>>(inputs, cls, nuniq, ccnt, cursor,
                                                 rlist, pbf);
    dim3 g(Rn / TRr, 4, Bn);
    k3_loss<<<g, 256, 0, stream>>>(xbf, pbf, roi, cmap, nuniq, mpart, spart, dlbl);
    k4_merge<<<1, 1024, 0, stream>>>(roi, nuniq, mpart, spart, dlbl, nvalid, out);
}

// Round 9
// 106.587 us; speedup vs baseline: 1.3743x; 1.3743x over previous
//
#include <hip/hip_runtime.h>
#include <math.h>

#define Bn 32
#define Rn 512
#define Dn 256
#define Pn 5532
#define MAXU 512
#define NEGBIG -3.0e38f

typedef short short8 __attribute__((ext_vector_type(8)));
typedef short short4v __attribute__((ext_vector_type(4)));
typedef float floatx4 __attribute__((ext_vector_type(4)));

// ---- workspace layout (4-byte words). NOTHING is host-zeroed; nll/ticket are
// zeroed by k1 each call; every other word read is written earlier in-call.
#define XBF_OFF    0
#define XBF_WORDS  (Bn*Rn*Dn/2)
#define PBF_OFF    (XBF_OFF + XBF_WORDS)
#define PBF_WORDS  (Bn*MAXU*Dn/2)
#define CMAP_OFF   (PBF_OFF + PBF_WORDS)
#define CCNT_OFF   (CMAP_OFF + Bn*Pn)
#define CURS_OFF   (CCNT_OFF + Bn*MAXU)
#define RLIST_OFF  (CURS_OFF + Bn*MAXU)
#define NUNIQ_OFF  (RLIST_OFF + Bn*Rn)
#define NVALID_OFF (NUNIQ_OFF + 32)
#define NLL_OFF    (NVALID_OFF + 32)
#define TICKET_OFF (NLL_OFF + 1)
#define MPART_OFF  (TICKET_OFF + 3)
#define SPART_OFF  (MPART_OFF + Bn*Rn*4)
#define DLBL_OFF   (SPART_OFF + Bn*Rn*4)
// end ~= 4.57M words ~= 18.3 MB

__device__ __forceinline__ unsigned short bf16r(float f) {   // fp32 -> bf16 RNE
    union { float f; unsigned int u; } c; c.f = f;
    return (unsigned short)((c.u + 0x7FFFu + ((c.u >> 16) & 1u)) >> 16);
}

// async global->LDS, 16B per lane. LDS dest = wave-uniform base + lane*16.
__device__ __forceinline__ void async16(void* lds, const void* g) {
    auto* l3 = reinterpret_cast<__attribute__((address_space(3))) unsigned int*>(
                   reinterpret_cast<size_t>(lds));
    auto* g1 = reinterpret_cast<const __attribute__((address_space(1))) unsigned int*>(
                   reinterpret_cast<size_t>(g));
    __builtin_amdgcn_global_load_lds(g1, l3, 16, 0, 0);
}

// ======== k1: blocks 0..31 = in-LDS per-image compact; blocks 32..543 = convert ======
__global__ __launch_bounds__(1024) void k1_prep_compact(
    const float* __restrict__ inputs, const float* __restrict__ cls,
    const int* __restrict__ roi_label,
    unsigned short* __restrict__ xbf,
    int* __restrict__ cmap, int* __restrict__ ccnt, int* __restrict__ cursor,
    int* __restrict__ rlist, int* __restrict__ nuniq, int* __restrict__ nvalid_arr,
    float* __restrict__ nll, int* __restrict__ ticket)
{
    const int flat = blockIdx.x;
    const int t = threadIdx.x;

    __shared__ int cnt_lds[Pn];                       // 22.1 KB
    __shared__ int cmap_lds[Pn];                      // 22.1 KB
    __shared__ int curs_lds[MAXU];
    __shared__ int wpres[16], wcnt[16];

    if (flat >= 32) {
        if (flat == 32 && t == 0) { nll[0] = 0.f; ticket[0] = 0; }  // replay reset
        // ---- convert inputs*cls -> bf16: 512 blocks x 1024 thr x 8 elems ----
        int g = (flat - 32) * 1024 + t;               // 0..524287
        int e = g * 8;
        int row = e >> 8;                             // /Dn
        float cw = cls[row];
        float4 v0 = *(const float4*)&inputs[e];
        float4 v1 = *(const float4*)&inputs[e + 4];
        short8 o;
        o[0] = (short)bf16r(v0.x * cw); o[1] = (short)bf16r(v0.y * cw);
        o[2] = (short)bf16r(v0.z * cw); o[3] = (short)bf16r(v0.w * cw);
        o[4] = (short)bf16r(v1.x * cw); o[5] = (short)bf16r(v1.y * cw);
        o[6] = (short)bf16r(v1.z * cw); o[7] = (short)bf16r(v1.w * cw);
        *(short8*)&xbf[e] = o;
        return;
    }

    // ---- per-image compact (counts built in LDS from this image's 512 labels) ----
    const int b = flat;
    const int lane = t & 63, wid = t >> 6;            // 16 waves
    for (int i = t; i < Pn; i += 1024) cnt_lds[i] = 0;
    __syncthreads();
    if (t < Rn) {
        int lbl = roi_label[b * Rn + t] - 1;
        if (lbl >= 0) atomicAdd(&cnt_lds[lbl], 1);
    }
    __syncthreads();

    int basePres = 0, baseCnt = 0;                    // replicated in all threads
    for (int i0 = 0; i0 < Pn; i0 += 1024) {
        int i = i0 + t;
        int cnt = (i < Pn) ? cnt_lds[i] : 0;
        bool pres = cnt > 0;
        unsigned long long mask = __ballot(pres);
        int pfx_pres = __popcll(mask & ((1ULL << lane) - 1ULL));
        int v = cnt;
        #pragma unroll
        for (int off = 1; off < 64; off <<= 1) {
            int u = __shfl_up(v, off);
            if (lane >= off) v += u;
        }
        int pfx_cnt = v - cnt;                        // exclusive
        if (lane == 63) { wpres[wid] = __popcll(mask); wcnt[wid] = v; }
        __syncthreads();
        int woffP = 0, totP = 0, woffC = 0, totC = 0;
        #pragma unroll
        for (int w = 0; w < 16; ++w) {
            int p = wpres[w], c = wcnt[w];
            if (w < wid) { woffP += p; woffC += c; }
            totP += p; totC += c;
        }
        if (pres) {
            int c = basePres + woffP + pfx_pres;      // compact slot < MAXU
            cmap_lds[i] = c;
            cmap[b * Pn + i] = c;                     // k3 lookup
            ccnt[b * MAXU + c] = cnt;
            curs_lds[c] = baseCnt + woffC + pfx_cnt;  // start offset
        }
        basePres += totP; baseCnt += totC;
        __syncthreads();
    }
    // scatter this image's 512 ROIs via LDS atomics
    if (t < Rn) {
        int lbl = roi_label[b * Rn + t] - 1;
        if (lbl >= 0) {
            int c = cmap_lds[lbl];
            int pos = atomicAdd(&curs_lds[c], 1);
            rlist[b * Rn + pos] = t;
        }
    }
    __syncthreads();
    if (t < MAXU && t < basePres)
        cursor[b * MAXU + t] = curs_lds[t];           // end offset (= start + cnt)
    if (t == 0) { nuniq[b] = basePres; nvalid_arr[b] = baseCnt; }
}

// ======== k2: gather -> mean -> L2 normalize -> bf16 proto (one slot per WAVE) ======
__global__ __launch_bounds__(256) void k2_proto(
    const float* __restrict__ inputs, const float* __restrict__ cls,
    const int* __restrict__ nuniq, const int* __restrict__ ccnt,
    const int* __restrict__ cursor, const int* __restrict__ rlist,
    unsigned short* __restrict__ pbf)
{
    const int lane = threadIdx.x & 63, wv = threadIdx.x >> 6;
    int s = blockIdx.x * 4 + wv;                      // 4096 blocks -> 16384 slots
    int b = s >> 9;
    int c = s & (MAXU - 1);
    if (c >= nuniq[b]) return;
    int cnt = ccnt[s];
    int start = cursor[s] - cnt;
    float4 acc = make_float4(0.f, 0.f, 0.f, 0.f);
    for (int k = 0; k < cnt; ++k) {
        int r = rlist[b * Rn + start + k];
        float cw = cls[b * Rn + r];
        float4 v = *(const float4*)&inputs[(size_t)(b * Rn + r) * Dn + lane * 4];
        acc.x += v.x * cw; acc.y += v.y * cw; acc.z += v.z * cw; acc.w += v.w * cw;
    }
    float inv = 1.0f / (float)cnt;
    acc.x *= inv; acc.y *= inv; acc.z *= inv; acc.w *= inv;
    float ss = acc.x*acc.x + acc.y*acc.y + acc.z*acc.z + acc.w*acc.w;
    #pragma unroll
    for (int off = 32; off > 0; off >>= 1) ss += __shfl_xor(ss, off);
    float scale = 1.0f / fmaxf(sqrtf(ss), 1e-12f);
    short4v o;
    o[0] = (short)bf16r(acc.x * scale); o[1] = (short)bf16r(acc.y * scale);
    o[2] = (short)bf16r(acc.z * scale); o[3] = (short)bf16r(acc.w * scale);
    *(short4v*)&pbf[(size_t)s * Dn + lane * 4] = o;
}

// ======== k3: bf16 MFMA GEMM, 128x128 tiles, async dbuf LDS + logsumexp ========
// grid (rt=4, b=32, pc=4): pc-siblings differ by 128 in flat id == 0 mod 8 ->
// same XCD under round-robin -> shared x-tile served from one L2 (heuristic).
#define TRr 128
#define TCc 128
#define KCk 32

__global__ __launch_bounds__(256, 3) void k3_loss(
    const unsigned short* __restrict__ xbf, const unsigned short* __restrict__ pbf,
    const int* __restrict__ roi_label, const int* __restrict__ cmap,
    const int* __restrict__ nuniq,
    float* __restrict__ mpart, float* __restrict__ spart,
    float* __restrict__ dlbl_arr)
{
    // XOR-swizzled bf16 tiles (content group g at gpos = g ^ ((row>>1)&3)),
    // realized via per-lane GLOBAL address; LDS side stays lane*16-linear.
    __shared__ __align__(16) unsigned short xs[2][TRr * KCk];   // 2 x 8 KB
    __shared__ __align__(16) unsigned short ps[2][TCc * KCk];   // 2 x 8 KB
    __shared__ int lblc[TRr];
    __shared__ float mw[4][TRr], sw[4][TRr];

    const int t = threadIdx.x;
    const int lane = t & 63, w = t >> 6;
    const int q = lane >> 4, r15 = lane & 15;
    const int b = blockIdx.y;
    const int pc = blockIdx.z;
    const int roiBase = blockIdx.x * TRr;
    const int U = nuniq[b];
    if (pc * TCc >= U) return;                        // uniform block exit

    if (t < TRr) {
        int lbl = roi_label[b * Rn + roiBase + t] - 1;
        lblc[t] = (lbl >= 0) ? cmap[b * Pn + lbl] : -1;
    }

    // 16 chunks/stage (8 xs + 8 ps); wave w stages xs {w, w+4}, ps {w, w+4}.
    int xrow[2], xg[2];
    #pragma unroll
    for (int cc = 0; cc < 2; ++cc) {
        int s = (w + cc * 4) * 64 + lane;
        xrow[cc] = s >> 2; xg[cc] = (s & 3) ^ ((xrow[cc] >> 1) & 3);
    }

    #define ISSUE(kc, buf)                                                         \
        do {                                                                       \
            async16(&xs[buf][w * 512],                                             \
                    xbf + (size_t)(b * Rn + roiBase + xrow[0]) * Dn                \
                        + (kc) * KCk + xg[0] * 8);                                 \
            async16(&xs[buf][(w + 4) * 512],                                       \
                    xbf + (size_t)(b * Rn + roiBase + xrow[1]) * Dn                \
                        + (kc) * KCk + xg[1] * 8);                                 \
            async16(&ps[buf][w * 512],                                             \
                    pbf + (size_t)(b * MAXU + pc * TCc + xrow[0]) * Dn             \
                        + (kc) * KCk + xg[0] * 8);                                 \
            async16(&ps[buf][(w + 4) * 512],                                       \
                    pbf + (size_t)(b * MAXU + pc * TCc + xrow[1]) * Dn             \
                        + (kc) * KCk + xg[1] * 8);                                 \
        } while (0)

    ISSUE(0, 0);

    floatx4 acc[8][2];
    #pragma unroll
    for (int mt = 0; mt < 8; ++mt)
        #pragma unroll
        for (int nt = 0; nt < 2; ++nt) acc[mt][nt] = (floatx4)0.f;

    for (int kc = 0; kc < Dn / KCk; ++kc) {           // 8 stages
        const int cur = kc & 1;
        __syncthreads();                              // buf[cur] resident
        if (kc < Dn / KCk - 1) ISSUE(kc + 1, cur ^ 1);

        short8 bb[2];
        #pragma unroll
        for (int nt = 0; nt < 2; ++nt) {
            int row = w * 32 + nt * 16 + r15;
            int off = row * KCk + ((q ^ ((row >> 1) & 3)) * 8);
            bb[nt] = *(const short8*)&ps[cur][off];
        }
        #pragma unroll
        for (int mt = 0; mt < 8; ++mt) {
            int row = mt * 16 + r15;
            int off = row * KCk + ((q ^ ((row >> 1) & 3)) * 8);
            short8 a = *(const short8*)&xs[cur][off];
            acc[mt][0] = __builtin_amdgcn_mfma_f32_16x16x32_bf16(a, bb[0], acc[mt][0], 0, 0, 0);
            acc[mt][1] = __builtin_amdgcn_mfma_f32_16x16x32_bf16(a, bb[1], acc[mt][1], 0, 0, 0);
        }
    }
    #undef ISSUE

    // ---- epilogue: masked logsumexp; C/D layout n = r15, m = q*4 + reg (tile mt) ----
    const int c0 = pc * TCc + w * 32 + r15;
    const int c1 = c0 + 16;
    const bool v0 = c0 < U, v1 = c1 < U;
    #pragma unroll
    for (int mt = 0; mt < 8; ++mt)
        #pragma unroll
        for (int reg = 0; reg < 4; ++reg) {
            int mloc = mt * 16 + q * 4 + reg;
            float d0 = acc[mt][0][reg], d1 = acc[mt][1][reg];
            int lc = lblc[mloc];
            if (v0 && c0 == lc) dlbl_arr[b * Rn + roiBase + mloc] = d0;  // unique writer
            if (v1 && c1 == lc) dlbl_arr[b * Rn + roiBase + mloc] = d1;
            float M = fmaxf(v0 ? d0 : NEGBIG, v1 ? d1 : NEGBIG);
            #pragma unroll
            for (int off = 1; off < 16; off <<= 1) M = fmaxf(M, __shfl_xor(M, off));
            float s = (v0 ? __expf(d0 - M) : 0.f) + (v1 ? __expf(d1 - M) : 0.f);
            #pragma unroll
            for (int off = 1; off < 16; off <<= 1) s += __shfl_xor(s, off);
            if (r15 == 0) { mw[w][mloc] = M; sw[w][mloc] = s; }
        }
    __syncthreads();

    if (t < TRr) {
        float M = fmaxf(fmaxf(mw[0][t], mw[1][t]), fmaxf(mw[2][t], mw[3][t]));
        float s = 0.f;
        #pragma unroll
        for (int wv = 0; wv < 4; ++wv) s += sw[wv][t] * __expf(mw[wv][t] - M);
        int roi = b * Rn + roiBase + t;
        mpart[roi * 4 + pc] = M;
        spart[roi * 4 + pc] = s;
    }
}

// ======== k4: 64-block merge -> NLL sum; last block (ticket) finalizes ========
__global__ __launch_bounds__(256) void k4_merge(
    const int* __restrict__ roi_label, const int* __restrict__ nuniq,
    const float* __restrict__ mpart, const float* __restrict__ spart,
    const float* __restrict__ dlbl_arr, float* __restrict__ nll_sum,
    int* __restrict__ ticket, const int* __restrict__ nvalid_arr,
    float* __restrict__ out)
{
    __shared__ float wsum[4];
    int roi = blockIdx.x * 256 + threadIdx.x;
    int b = roi >> 9;
    int lbl = roi_label[roi] - 1;
    float v = 0.f;
    if (lbl >= 0) {
        int U = nuniq[b];
        int nch = (U + TCc - 1) / TCc;
        float m = NEGBIG, s = 0.f;
        for (int pc = 0; pc < nch; ++pc) {
            float om = mpart[roi * 4 + pc], os = spart[roi * 4 + pc];
            float M = fmaxf(m, om);
            s = s * __expf(m - M) + os * __expf(om - M);
            m = M;
        }
        v = m + __logf(s) - dlbl_arr[roi];
    }
    #pragma unroll
    for (int off = 1; off < 64; off <<= 1) v += __shfl_xor(v, off);
    int lane = threadIdx.x & 63, wid = threadIdx.x >> 6;
    if (lane == 0) wsum[wid] = v;
    __syncthreads();
    if (threadIdx.x == 0) {
        atomicAdd(nll_sum, wsum[0] + wsum[1] + wsum[2] + wsum[3]);
        __threadfence();
        int tk = atomicAdd(ticket, 1);
        if (tk == gridDim.x - 1) {                    // last block finalizes
            __threadfence();
            int s = 0;
            #pragma unroll
            for (int bb = 0; bb < Bn; ++bb) s += nvalid_arr[bb];
            out[0] = nll_sum[0] / fmaxf((float)s, 1.0f);
        }
    }
}

extern "C" void kernel_launch(void* const* d_in, const int* in_sizes, int n_in,
                              void* d_out, int out_size, void* d_ws, size_t ws_size,
                              hipStream_t stream) {
    const float* inputs = (const float*)d_in[0];
    const float* cls    = (const float*)d_in[1];
    const int*   roi    = (const int*)d_in[2];
    float* out = (float*)d_out;

    float* wsf = (float*)d_ws;
    int*   wsi = (int*)d_ws;
    unsigned short* xbf = (unsigned short*)(wsi + XBF_OFF);
    unsigned short* pbf = (unsigned short*)(wsi + PBF_OFF);
    int*   cmap   = wsi + CMAP_OFF;
    int*   ccnt   = wsi + CCNT_OFF;
    int*   cursor = wsi + CURS_OFF;
    int*   rlist  = wsi + RLIST_OFF;
    int*   nuniq  = wsi + NUNIQ_OFF;
    int*   nvalid = wsi + NVALID_OFF;
    float* nll    = wsf + NLL_OFF;
    int*   ticket = wsi + TICKET_OFF;
    float* mpart  = wsf + MPART_OFF;
    float* spart  = wsf + SPART_OFF;
    float* dlbl   = wsf + DLBL_OFF;

    k1_prep_compact<<<32 + 512, 1024, 0, stream>>>(inputs, cls, roi, xbf, cmap, ccnt,
                                                   cursor, rlist, nuniq, nvalid,
                                                   nll, ticket);
    k2_proto<<<(Bn * MAXU) / 4, 256, 0, stream>>>(inputs, cls, nuniq, ccnt, cursor,
                                                  rlist, pbf);
    dim3 g(Rn / TRr, Bn, 4);
    k3_loss<<<g, 256, 0, stream>>>(xbf, pbf, roi, cmap, nuniq, mpart, spart, dlbl);
    k4_merge<<<(Bn * Rn) / 256, 256, 0, stream>>>(roi, nuniq, mpart, spart, dlbl, nll,
                                                  ticket, nvalid, out);
}